// Round 14
// baseline (520.993 us; speedup 1.0000x reference)
//
#include <hip/hip_runtime.h>
#include <hip/hip_bf16.h>
#include <stdint.h>

#define NN    100000
#define NROWP 100096   // padded rows (gemm tail reads up to 100031)
#define NE    1600000
#define FIN   128
#define FOUT  200
#define NBLK  391      // ceil(NN/256)

typedef __attribute__((ext_vector_type(8))) short short8;
typedef __attribute__((ext_vector_type(8))) unsigned short ushort8;
typedef __attribute__((ext_vector_type(2))) float f32x2;
typedef __attribute__((ext_vector_type(4))) float f32x4;
typedef __attribute__((ext_vector_type(2))) unsigned int u32x2;
typedef __attribute__((ext_vector_type(4))) unsigned int uint32x4;

__device__ __forceinline__ short f2bf(float f) {
    __hip_bfloat16 h = __float2bfloat16(f);
    return *reinterpret_cast<short*>(&h);
}
__device__ __forceinline__ unsigned short f2bfu(float f) {
    __hip_bfloat16 h = __float2bfloat16(f);
    return *reinterpret_cast<unsigned short*>(&h);
}
__device__ __forceinline__ float bf2f(unsigned short u) {
    return __uint_as_float((unsigned)u << 16);
}
__device__ __forceinline__ int getidx(const void* ei, int isI32, long long i) {
    return isI32 ? ((const int*)ei)[i] : (int)((const long long*)ei)[i];
}

// --- dtype detection: read edge_index as int64; if any value out of [0,NN), it is int32 ---
__global__ void detect_kernel(const long long* ei64, int* flag) {
    int t = blockIdx.x * blockDim.x + threadIdx.x;   // 4096 samples
    long long v = ei64[t];
    if (v < 0 || v >= NN) atomicOr(flag, 1);
}

// per-replica histogram of destination rows; rep = blockIdx & 7 (XCD round-robin)
__global__ void cnt8_kernel(const void* ei, const int* flag, int* cnt8) {
    int e = blockIdx.x * blockDim.x + threadIdx.x;   // NE exact
    int r = getidx(ei, *flag, e);
    atomicAdd(&cnt8[(blockIdx.x & 7) * NN + r], 1);
}

// fused: per-row 8-replica prefix + block-level exclusive scan of row totals
__global__ void scan_block(int* __restrict__ cnt8, int* __restrict__ rowstart,
                           int* __restrict__ bsum) {
    __shared__ int tmp[256];
    int i = blockIdx.x * 256 + threadIdx.x;
    int v = 0;
    if (i < NN) {
        int s = 0;
        #pragma unroll
        for (int x = 0; x < 8; ++x) {
            int c = cnt8[x * NN + i];
            cnt8[x * NN + i] = s;   // replica exclusive prefix within row
            s += c;
        }
        v = s;
    }
    tmp[threadIdx.x] = v;
    __syncthreads();
    for (int off = 1; off < 256; off <<= 1) {
        int t = (threadIdx.x >= off) ? tmp[threadIdx.x - off] : 0;
        __syncthreads();
        tmp[threadIdx.x] += t;
        __syncthreads();
    }
    if (i < NN) rowstart[i] = tmp[threadIdx.x] - v;
    if (threadIdx.x == 255) bsum[blockIdx.x] = tmp[255];
}

__global__ void scan_bsums(int* bsum) {   // 1 block, 512 threads
    __shared__ int tmp[512];
    int t = threadIdx.x;
    int v = (t < NBLK) ? bsum[t] : 0;
    tmp[t] = v;
    __syncthreads();
    for (int off = 1; off < 512; off <<= 1) {
        int u = (t >= off) ? tmp[t - off] : 0;
        __syncthreads();
        tmp[t] += u;
        __syncthreads();
    }
    if (t < NBLK) bsum[t] = tmp[t] - v;
}

__global__ void scan_add(int* __restrict__ rowstart, const int* __restrict__ bsum) {
    int i = blockIdx.x * 256 + threadIdx.x;
    if (i < NN)       rowstart[i] += bsum[i >> 8];
    else if (i == NN) rowstart[NN] = NE;
}

// counting-sort edges by destination row; rec = {col, w_bits}; position from
// rowstart + per-replica prefix + XCD-local atomic bump.
__global__ void fill_csr(const void* ei, const int* flag, const float* __restrict__ w,
                         const int* __restrict__ rowstart, int* __restrict__ cnt8,
                         int2* __restrict__ edge) {
    int e = blockIdx.x * blockDim.x + threadIdx.x;   // NE exact; SAME grid as cnt8_kernel
    int isI32 = *flag;
    int r = getidx(ei, isI32, e);
    int c = getidx(ei, isI32, (long long)NE + e);
    int pos = rowstart[r] + atomicAdd(&cnt8[(blockIdx.x & 7) * NN + r], 1);
    int2 rec; rec.x = c; rec.y = __float_as_int(w[e]);
    edge[pos] = rec;
}

// per-row segmented sum of sorted weights -> dis[r] = deg>0 ? rsqrt(deg) : 0
__global__ void deg_seg(const int* __restrict__ rowstart, const int2* __restrict__ edge,
                        float* __restrict__ dis) {
    int r = blockIdx.x * 256 + threadIdx.x;
    if (r >= NN) return;
    int s = rowstart[r], e = rowstart[r + 1];
    float d = 0.f;
    for (int i = s; i < e; ++i) d += __int_as_float(edge[i].y);
    dis[r] = d > 0.f ? rsqrtf(d) : 0.f;
}

// fused conversion: Xb = bf16(x); Xs8 = fp8_e4m3(dis * x).  NT stores (write-once).
__global__ void xconv_kernel(const float* __restrict__ x, const float* __restrict__ dis,
                             unsigned short* __restrict__ xb, unsigned int* __restrict__ xs8) {
    int i = blockIdx.x * 256 + threadIdx.x;   // NN*16 exact; 8 values/thread
    float d = dis[i >> 4];
    long long base = (long long)i * 8;
    f32x4 v0 = *(const f32x4*)(x + base);
    f32x4 v1 = *(const f32x4*)(x + base + 4);
    ushort8 o;
    #pragma unroll
    for (int k = 0; k < 4; ++k) { o[k] = f2bfu(v0[k]); o[4 + k] = f2bfu(v1[k]); }
    __builtin_nontemporal_store(o, (ushort8*)(xb + base));
    unsigned u0 = __builtin_amdgcn_cvt_pk_fp8_f32(d * v0[0], d * v0[1], 0, false);
    u0 = __builtin_amdgcn_cvt_pk_fp8_f32(d * v0[2], d * v0[3], u0, true);
    unsigned u1 = __builtin_amdgcn_cvt_pk_fp8_f32(d * v1[0], d * v1[1], 0, false);
    u1 = __builtin_amdgcn_cvt_pk_fp8_f32(d * v1[2], d * v1[3], u1, true);
    u32x2 ov; ov[0] = u0; ov[1] = u1;
    __builtin_nontemporal_store(ov, (u32x2*)(xs8 + (long long)i * 2));
}

// first propagation pass: one wave per row, quarter-wave per edge, 2 in flight.
// T1 = -dis[r] * sum_e w_e * Xs8[c_e]; emits T1b (bf16) and T1s8 = fp8(dis[r]*T1).
__launch_bounds__(256)
__global__ void gather1(const int* __restrict__ rowstart, const int2* __restrict__ edge,
                        const float* __restrict__ dis,
                        const unsigned int* __restrict__ src8,
                        unsigned short* __restrict__ dstb,
                        unsigned int* __restrict__ dst8) {
    int gw   = (blockIdx.x << 2) + (threadIdx.x >> 6);   // row
    int lane = threadIdx.x & 63;
    int q = lane >> 4, fl = lane & 15;                   // quarter, 8B chunk
    int s = rowstart[gw], eend = rowstart[gw + 1];
    float a0[8] = {0.f,0.f,0.f,0.f,0.f,0.f,0.f,0.f};
    float a1[8] = {0.f,0.f,0.f,0.f,0.f,0.f,0.f,0.f};
    int e = s + q;
    for (; e + 4 < eend; e += 8) {   // 2 edges in flight per quarter
        int2 ed0 = edge[e];
        int2 ed1 = edge[e + 4];
        u32x2 v0 = *(const u32x2*)(src8 + ((long long)ed0.x << 5) + (fl << 1));
        u32x2 v1 = *(const u32x2*)(src8 + ((long long)ed1.x << 5) + (fl << 1));
        float w0 = __int_as_float(ed0.y);
        float w1 = __int_as_float(ed1.y);
        f32x2 p0 = __builtin_amdgcn_cvt_pk_f32_fp8(v0[0], false);
        f32x2 p1 = __builtin_amdgcn_cvt_pk_f32_fp8(v0[0], true);
        f32x2 p2 = __builtin_amdgcn_cvt_pk_f32_fp8(v0[1], false);
        f32x2 p3 = __builtin_amdgcn_cvt_pk_f32_fp8(v0[1], true);
        a0[0] += w0 * p0.x; a0[1] += w0 * p0.y; a0[2] += w0 * p1.x; a0[3] += w0 * p1.y;
        a0[4] += w0 * p2.x; a0[5] += w0 * p2.y; a0[6] += w0 * p3.x; a0[7] += w0 * p3.y;
        f32x2 r0 = __builtin_amdgcn_cvt_pk_f32_fp8(v1[0], false);
        f32x2 r1 = __builtin_amdgcn_cvt_pk_f32_fp8(v1[0], true);
        f32x2 r2 = __builtin_amdgcn_cvt_pk_f32_fp8(v1[1], false);
        f32x2 r3 = __builtin_amdgcn_cvt_pk_f32_fp8(v1[1], true);
        a1[0] += w1 * r0.x; a1[1] += w1 * r0.y; a1[2] += w1 * r1.x; a1[3] += w1 * r1.y;
        a1[4] += w1 * r2.x; a1[5] += w1 * r2.y; a1[6] += w1 * r3.x; a1[7] += w1 * r3.y;
    }
    if (e < eend) {
        int2 ed = edge[e];
        u32x2 v = *(const u32x2*)(src8 + ((long long)ed.x << 5) + (fl << 1));
        float w = __int_as_float(ed.y);
        f32x2 p0 = __builtin_amdgcn_cvt_pk_f32_fp8(v[0], false);
        f32x2 p1 = __builtin_amdgcn_cvt_pk_f32_fp8(v[0], true);
        f32x2 p2 = __builtin_amdgcn_cvt_pk_f32_fp8(v[1], false);
        f32x2 p3 = __builtin_amdgcn_cvt_pk_f32_fp8(v[1], true);
        a0[0] += w * p0.x; a0[1] += w * p0.y; a0[2] += w * p1.x; a0[3] += w * p1.y;
        a0[4] += w * p2.x; a0[5] += w * p2.y; a0[6] += w * p3.x; a0[7] += w * p3.y;
    }
    #pragma unroll
    for (int i = 0; i < 8; ++i) {
        a0[i] += a1[i];
        a0[i] += __shfl_xor(a0[i], 16);
        a0[i] += __shfl_xor(a0[i], 32);
    }
    if (lane < 16) {
        float sr = -dis[gw];
        float t[8];
        ushort8 o;
        #pragma unroll
        for (int i = 0; i < 8; ++i) { t[i] = sr * a0[i]; o[i] = f2bfu(t[i]); }
        __builtin_nontemporal_store(o, (ushort8*)(dstb + ((long long)gw << 7) + (fl << 3)));
        float ds = dis[gw];
        unsigned u0 = __builtin_amdgcn_cvt_pk_fp8_f32(ds * t[0], ds * t[1], 0, false);
        u0 = __builtin_amdgcn_cvt_pk_fp8_f32(ds * t[2], ds * t[3], u0, true);
        unsigned u1 = __builtin_amdgcn_cvt_pk_fp8_f32(ds * t[4], ds * t[5], 0, false);
        u1 = __builtin_amdgcn_cvt_pk_fp8_f32(ds * t[6], ds * t[7], u1, true);
        u32x2 ov; ov[0] = u0; ov[1] = u1;
        __builtin_nontemporal_store(ov, (u32x2*)(dst8 + ((long long)gw << 5) + (fl << 1)));
    }
}

// ---------------------------------------------------------------------------
// Weight prep: pack W into MFMA B-fragment order.
// Frag unit (tile t, kstep ks) of scale s at unit index fb(s) + t*nk + ks,
// nk = 4(s+1), fb = {0, 52, 156}.  Lane l holds W_s[k=ks*32+(l>>4)*8+i][col=t*16+(l&15)].
// ---------------------------------------------------------------------------
__global__ void wprep_frag(const float* __restrict__ W1, const float* __restrict__ W2,
                           const float* __restrict__ W3, short* __restrict__ Wf) {
    __shared__ float lds[32 * 200];
    int bid = blockIdx.x;
    int s, ks;
    if (bid < 4)       { s = 0; ks = bid; }
    else if (bid < 12) { s = 1; ks = bid - 4; }
    else               { s = 2; ks = bid - 12; }
    const float* W = (s == 0) ? W1 : ((s == 1) ? W2 : W3);
    int p = ks >> 2;
    const float* Wp = W + (p * 128 + (ks & 3) * 32) * 200;
    for (int e = threadIdx.x; e < 6400; e += 256) lds[e] = Wp[e];
    __syncthreads();
    int nk = (s + 1) * 4;
    int fb = (s == 0) ? 0 : ((s == 1) ? 52 : 156);
    for (int qq = threadIdx.x; qq < 13 * 64; qq += 256) {
        int t = qq >> 6, lane = qq & 63;
        int col = t * 16 + (lane & 15);
        int kb  = (lane >> 4) * 8;
        short8 v;
        #pragma unroll
        for (int i = 0; i < 8; ++i) {
            float f = (col < FOUT) ? lds[(kb + i) * 200 + col] : 0.f;
            v[i] = f2bf(f);
        }
        *(short8*)&Wf[(fb + t * nk + ks) * 512 + lane * 8] = v;
    }
}

// ---------------------------------------------------------------------------
// Fused GEMM + second propagation: 512 threads = 8 waves, BM=64.
// Stage panels x, T1 from global; compute panel T2 IN-BLOCK via gather from
// T1s8 (8 waves x 8 rows, quarter-wave/2-deep), writing bf16 straight into
// the swizzled As panel-2 slot.  Then the proven 39-unit MFMA loop + LDS
// transpose epilogue with NT stores.  T2 never exists in global memory.
// ---------------------------------------------------------------------------
__constant__ int u_sc[8][5] = {
    {2,2,1,0,0}, {2,2,1,0,0}, {2,2,1,0,0}, {2,2,1,0,0},
    {2,2,1,0,0}, {2,2,1,0,0}, {2,1,1,1,0}, {1,1,1,1,-1}};
__constant__ int u_t[8][5] = {
    {0,1,0,0,1},     {2,3,1,2,3},    {4,5,2,4,5},    {6,7,3,6,7},
    {8,9,4,8,9},     {10,11,5,10,11},{12,6,7,8,12},  {9,10,11,12,0}};

#define EPAD 204   // f32 row stride in epilogue LDS (52224B total)

__launch_bounds__(512, 2)
__global__ void gemm_fused(const unsigned short* __restrict__ xb,
                           const unsigned short* __restrict__ t1b,
                           const short* __restrict__ Wf,
                           const float* __restrict__ b1, const float* __restrict__ b2,
                           const float* __restrict__ b3, float* __restrict__ out,
                           const int* __restrict__ rowstart, const int2* __restrict__ edge,
                           const float* __restrict__ dis,
                           const unsigned int* __restrict__ t1s8) {
    __shared__ __align__(16) char smem[64 * EPAD * 4];   // 52224B >= 49152B As
    short* As = (short*)smem;                             // [3][64][16 chunks][8]
    float* Ef = (float*)smem;                             // [64][EPAD]

    const int tid  = threadIdx.x;
    const int wave = tid >> 6;
    const int lane = tid & 63;
    const int l15  = lane & 15;
    const int lhi  = lane >> 4;
    const int b0   = blockIdx.x * 64;

    // stage panels 0 (x), 1 (T1): 2048 chunks of 16B, 4 per thread
    const unsigned short* panels[2] = {xb, t1b};
    #pragma unroll
    for (int i = 0; i < 4; ++i) {
        int q   = i * 512 + tid;
        int p   = q >> 10;
        int rem = q & 1023;
        int row = rem >> 4;
        int ch  = rem & 15;
        uint32x4 v = *(const uint32x4*)(panels[p] + ((long long)(b0 + row) << 7) + (ch << 3));
        *(uint32x4*)&As[((p * 64 + row) * 16 + (ch ^ (row & 7))) * 8] = v;
    }

    // panel 2 (T2) via in-block gather: wave handles rows wave*8 .. wave*8+7
    {
        const int q = lane >> 4, fl = lane & 15;
        for (int rr = 0; rr < 8; ++rr) {
            const int row = wave * 8 + rr;
            const int gw = b0 + row;
            int s = 0, eend = 0;
            if (gw < NN) { s = rowstart[gw]; eend = rowstart[gw + 1]; }
            float a0[8] = {0.f,0.f,0.f,0.f,0.f,0.f,0.f,0.f};
            float a1[8] = {0.f,0.f,0.f,0.f,0.f,0.f,0.f,0.f};
            int e = s + q;
            for (; e + 4 < eend; e += 8) {
                int2 ed0 = edge[e];
                int2 ed1 = edge[e + 4];
                u32x2 v0 = *(const u32x2*)(t1s8 + ((long long)ed0.x << 5) + (fl << 1));
                u32x2 v1 = *(const u32x2*)(t1s8 + ((long long)ed1.x << 5) + (fl << 1));
                float w0 = __int_as_float(ed0.y);
                float w1 = __int_as_float(ed1.y);
                f32x2 p0 = __builtin_amdgcn_cvt_pk_f32_fp8(v0[0], false);
                f32x2 p1 = __builtin_amdgcn_cvt_pk_f32_fp8(v0[0], true);
                f32x2 p2 = __builtin_amdgcn_cvt_pk_f32_fp8(v0[1], false);
                f32x2 p3 = __builtin_amdgcn_cvt_pk_f32_fp8(v0[1], true);
                a0[0] += w0 * p0.x; a0[1] += w0 * p0.y; a0[2] += w0 * p1.x; a0[3] += w0 * p1.y;
                a0[4] += w0 * p2.x; a0[5] += w0 * p2.y; a0[6] += w0 * p3.x; a0[7] += w0 * p3.y;
                f32x2 r0 = __builtin_amdgcn_cvt_pk_f32_fp8(v1[0], false);
                f32x2 r1 = __builtin_amdgcn_cvt_pk_f32_fp8(v1[0], true);
                f32x2 r2 = __builtin_amdgcn_cvt_pk_f32_fp8(v1[1], false);
                f32x2 r3 = __builtin_amdgcn_cvt_pk_f32_fp8(v1[1], true);
                a1[0] += w1 * r0.x; a1[1] += w1 * r0.y; a1[2] += w1 * r1.x; a1[3] += w1 * r1.y;
                a1[4] += w1 * r2.x; a1[5] += w1 * r2.y; a1[6] += w1 * r3.x; a1[7] += w1 * r3.y;
            }
            if (e < eend) {
                int2 ed = edge[e];
                u32x2 v = *(const u32x2*)(t1s8 + ((long long)ed.x << 5) + (fl << 1));
                float w = __int_as_float(ed.y);
                f32x2 p0 = __builtin_amdgcn_cvt_pk_f32_fp8(v[0], false);
                f32x2 p1 = __builtin_amdgcn_cvt_pk_f32_fp8(v[0], true);
                f32x2 p2 = __builtin_amdgcn_cvt_pk_f32_fp8(v[1], false);
                f32x2 p3 = __builtin_amdgcn_cvt_pk_f32_fp8(v[1], true);
                a0[0] += w * p0.x; a0[1] += w * p0.y; a0[2] += w * p1.x; a0[3] += w * p1.y;
                a0[4] += w * p2.x; a0[5] += w * p2.y; a0[6] += w * p3.x; a0[7] += w * p3.y;
            }
            #pragma unroll
            for (int i = 0; i < 8; ++i) {
                a0[i] += a1[i];
                a0[i] += __shfl_xor(a0[i], 16);
                a0[i] += __shfl_xor(a0[i], 32);
            }
            if (lane < 16) {
                float sr = (gw < NN) ? -dis[gw] : 0.f;
                ushort8 xv = *(const ushort8*)(xb + ((long long)gw << 7) + (fl << 3));
                ushort8 o;
                #pragma unroll
                for (int i = 0; i < 8; ++i) o[i] = f2bfu(2.f * sr * a0[i] - bf2f(xv[i]));
                *(ushort8*)&As[((128 + row) * 16 + (fl ^ (row & 7))) * 8] = o;
            }
        }
    }

    int usc[5], ubase[5], ucol0[5];
    #pragma unroll
    for (int j = 0; j < 5; ++j) {
        int sc = u_sc[wave][j], t = u_t[wave][j];
        usc[j]   = sc;
        ucol0[j] = t * 16;
        int nk = 4 * (sc + 1);
        int fb = (sc == 0) ? 0 : ((sc == 1) ? 52 : 156);
        ubase[j] = fb + t * nk;
    }

    f32x4 acc[5][4];
    #pragma unroll
    for (int j = 0; j < 5; ++j)
        #pragma unroll
        for (int m = 0; m < 4; ++m) acc[j][m] = {0.f, 0.f, 0.f, 0.f};

    short8 bf[2][5];
    #pragma unroll
    for (int j = 0; j < 5; ++j)
        bf[0][j] = *(const short8*)(Wf + (long long)(ubase[j] + 0) * 512 + lane * 8);

    __syncthreads();

    #pragma unroll
    for (int step = 0; step < 12; ++step) {
        const int p   = step >> 2;
        const int k4  = step & 3;
        const int cur = step & 1;
        if (step < 11) {
            #pragma unroll
            for (int j = 0; j < 5; ++j)
                bf[cur ^ 1][j] = *(const short8*)(Wf + (long long)(ubase[j] + step + 1) * 512 + lane * 8);
        }
        short8 af[4];
        #pragma unroll
        for (int m = 0; m < 4; ++m) {
            int row = m * 16 + l15;
            int ch  = (k4 * 4 + lhi) ^ (row & 7);
            af[m] = *(const short8*)&As[((p * 64 + row) * 16 + ch) * 8];
        }
        #pragma unroll
        for (int j = 0; j < 5; ++j) {
            if (usc[j] >= p) {   // wave-uniform branch; -1 sentinel never passes
                #pragma unroll
                for (int m = 0; m < 4; ++m)
                    acc[j][m] = __builtin_amdgcn_mfma_f32_16x16x32_bf16(af[m], bf[cur][j], acc[j][m], 0, 0, 0);
            }
        }
    }

    // epilogue: per scale, deposit to LDS then NT-store coalesced full rows
    #pragma unroll 1
    for (int sc = 0; sc < 3; ++sc) {
        __syncthreads();
        const float* bias = (sc == 0) ? b1 : ((sc == 1) ? b2 : b3);
        #pragma unroll
        for (int j = 0; j < 5; ++j) {
            if (usc[j] == sc) {
                int col = ucol0[j] + l15;
                if (col < FOUT) {
                    float bv = bias[col];
                    #pragma unroll
                    for (int m = 0; m < 4; ++m) {
                        int rbase = m * 16 + lhi * 4;
                        #pragma unroll
                        for (int jj = 0; jj < 4; ++jj)
                            Ef[(rbase + jj) * EPAD + col] = acc[j][m][jj] + bv;
                    }
                }
            }
        }
        __syncthreads();
        float* op = out + (long long)sc * NN * FOUT;
        for (int c = tid; c < 3200; c += 512) {   // 64 rows x 50 f32x4 chunks
            int r = c / 50, pos = c % 50;
            int row = b0 + r;
            if (row < NN) {
                f32x4 v = *(const f32x4*)&Ef[r * EPAD + pos * 4];
                __builtin_nontemporal_store(v, (f32x4*)&op[(long long)row * FOUT + pos * 4]);
            }
        }
    }
}

extern "C" void kernel_launch(void* const* d_in, const int* in_sizes, int n_in,
                              void* d_out, int out_size, void* d_ws, size_t ws_size,
                              hipStream_t stream) {
    const float* x  = (const float*)d_in[0];
    const void*  ei = d_in[1];
    const float* ew = (const float*)d_in[2];
    const float* W1 = (const float*)d_in[3];
    const float* b1 = (const float*)d_in[4];
    const float* W2 = (const float*)d_in[5];
    const float* b2 = (const float*)d_in[6];
    const float* W3 = (const float*)d_in[7];
    const float* b3 = (const float*)d_in[8];
    float* out = (float*)d_out;

    char* ws = (char*)d_ws;
    // layout (bytes):
    // [0,16)                  flag          } zeroed
    // [16, 3200016)           cnt8 8xN i32  } zeroed
    // [3600016, 4000032)      rowstart N+1 (padded)
    // [4000032, 4002080)      bsum 512
    // [4002080, 4402080)      dis  N f32
    // [4402080, 17202080)     edge int2 E
    // [17202080, 42826656)    Xb   bf16 NROWP*128
    // [42826656, 68451232)    T1b  bf16
    // [94075808, 94395296)    Wf   bf16 frags (312 KB)
    // [94395296, 107207584)   Xs8  fp8 NROWP*128
    // [107207584, 120019872)  T1s8 fp8 NROWP*128
    int*   flag     = (int*)(ws + 0);
    int*   cnt8     = (int*)(ws + 16);
    int*   rowstart = (int*)(ws + 3600016);
    int*   bsum     = (int*)(ws + 4000032);
    float* dis      = (float*)(ws + 4002080);
    int2*  edge     = (int2*)(ws + 4402080);
    unsigned short* Xb  = (unsigned short*)(ws + 17202080);
    unsigned short* T1b = (unsigned short*)(ws + 42826656);
    short* Wf       = (short*)(ws + 94075808);
    unsigned int* Xs8  = (unsigned int*)(ws + 94395296);
    unsigned int* T1s8 = (unsigned int*)(ws + 107207584);

    hipMemsetAsync(d_ws, 0, 3200016, stream);   // flag + cnt8

    detect_kernel<<<16, 256, 0, stream>>>((const long long*)ei, flag);
    cnt8_kernel<<<NE / 256, 256, 0, stream>>>(ei, flag, cnt8);
    scan_block<<<NBLK, 256, 0, stream>>>(cnt8, rowstart, bsum);
    scan_bsums<<<1, 512, 0, stream>>>(bsum);
    scan_add<<<NBLK + 1, 256, 0, stream>>>(rowstart, bsum);
    fill_csr<<<NE / 256, 256, 0, stream>>>(ei, flag, ew, rowstart, cnt8, edge);
    deg_seg<<<NBLK, 256, 0, stream>>>(rowstart, edge, dis);
    xconv_kernel<<<6250, 256, 0, stream>>>(x, dis, Xb, Xs8);
    gather1<<<NN / 4, 256, 0, stream>>>(rowstart, edge, dis, Xs8, T1b, T1s8);
    wprep_frag<<<24, 256, 0, stream>>>(W1, W2, W3, Wf);
    gemm_fused<<<1563, 512, 0, stream>>>(Xb, T1b, Wf, b1, b2, b3, out,
                                         rowstart, edge, dis, T1s8);
}

// Round 15
// 418.315 us; speedup vs baseline: 1.2455x; 1.2455x over previous
//
#include <hip/hip_runtime.h>
#include <hip/hip_bf16.h>
#include <stdint.h>

#define NN    100000
#define NROWP 100096   // padded rows (gemm tail reads up to 100031)
#define NE    1600000
#define FIN   128
#define FOUT  200
#define NBLK  391      // ceil(NN/256)

typedef __attribute__((ext_vector_type(8))) short short8;
typedef __attribute__((ext_vector_type(8))) unsigned short ushort8;
typedef __attribute__((ext_vector_type(2))) float f32x2;
typedef __attribute__((ext_vector_type(4))) float f32x4;
typedef __attribute__((ext_vector_type(2))) unsigned int u32x2;
typedef __attribute__((ext_vector_type(4))) unsigned int uint32x4;

__device__ __forceinline__ short f2bf(float f) {
    __hip_bfloat16 h = __float2bfloat16(f);
    return *reinterpret_cast<short*>(&h);
}
__device__ __forceinline__ unsigned short f2bfu(float f) {
    __hip_bfloat16 h = __float2bfloat16(f);
    return *reinterpret_cast<unsigned short*>(&h);
}
__device__ __forceinline__ float bf2f(unsigned short u) {
    return __uint_as_float((unsigned)u << 16);
}
__device__ __forceinline__ int getidx(const void* ei, int isI32, long long i) {
    return isI32 ? ((const int*)ei)[i] : (int)((const long long*)ei)[i];
}

// --- dtype detection: read edge_index as int64; if any value out of [0,NN), it is int32 ---
__global__ void detect_kernel(const long long* ei64, int* flag) {
    int t = blockIdx.x * blockDim.x + threadIdx.x;   // 4096 samples
    long long v = ei64[t];
    if (v < 0 || v >= NN) atomicOr(flag, 1);
}

// per-replica histogram of destination rows; rep = blockIdx & 7 (XCD round-robin)
__global__ void cnt8_kernel(const void* ei, const int* flag, int* cnt8) {
    int e = blockIdx.x * blockDim.x + threadIdx.x;   // NE exact
    int r = getidx(ei, *flag, e);
    atomicAdd(&cnt8[(blockIdx.x & 7) * NN + r], 1);
}

// fused: per-row 8-replica prefix + block-level exclusive scan of row totals
__global__ void scan_block(int* __restrict__ cnt8, int* __restrict__ rowstart,
                           int* __restrict__ bsum) {
    __shared__ int tmp[256];
    int i = blockIdx.x * 256 + threadIdx.x;
    int v = 0;
    if (i < NN) {
        int s = 0;
        #pragma unroll
        for (int x = 0; x < 8; ++x) {
            int c = cnt8[x * NN + i];
            cnt8[x * NN + i] = s;   // replica exclusive prefix within row
            s += c;
        }
        v = s;
    }
    tmp[threadIdx.x] = v;
    __syncthreads();
    for (int off = 1; off < 256; off <<= 1) {
        int t = (threadIdx.x >= off) ? tmp[threadIdx.x - off] : 0;
        __syncthreads();
        tmp[threadIdx.x] += t;
        __syncthreads();
    }
    if (i < NN) rowstart[i] = tmp[threadIdx.x] - v;
    if (threadIdx.x == 255) bsum[blockIdx.x] = tmp[255];
}

__global__ void scan_bsums(int* bsum) {   // 1 block, 512 threads
    __shared__ int tmp[512];
    int t = threadIdx.x;
    int v = (t < NBLK) ? bsum[t] : 0;
    tmp[t] = v;
    __syncthreads();
    for (int off = 1; off < 512; off <<= 1) {
        int u = (t >= off) ? tmp[t - off] : 0;
        __syncthreads();
        tmp[t] += u;
        __syncthreads();
    }
    if (t < NBLK) bsum[t] = tmp[t] - v;
}

__global__ void scan_add(int* __restrict__ rowstart, const int* __restrict__ bsum) {
    int i = blockIdx.x * 256 + threadIdx.x;
    if (i < NN)       rowstart[i] += bsum[i >> 8];
    else if (i == NN) rowstart[NN] = NE;
}

// counting-sort edges by destination row; rec = {col, w_bits}; position from
// rowstart + per-replica prefix + XCD-local atomic bump.
__global__ void fill_csr(const void* ei, const int* flag, const float* __restrict__ w,
                         const int* __restrict__ rowstart, int* __restrict__ cnt8,
                         int2* __restrict__ edge) {
    int e = blockIdx.x * blockDim.x + threadIdx.x;   // NE exact; SAME grid as cnt8_kernel
    int isI32 = *flag;
    int r = getidx(ei, isI32, e);
    int c = getidx(ei, isI32, (long long)NE + e);
    int pos = rowstart[r] + atomicAdd(&cnt8[(blockIdx.x & 7) * NN + r], 1);
    int2 rec; rec.x = c; rec.y = __float_as_int(w[e]);
    edge[pos] = rec;
}

// per-row segmented sum of sorted weights -> dis[r] = deg>0 ? rsqrt(deg) : 0
__global__ void deg_seg(const int* __restrict__ rowstart, const int2* __restrict__ edge,
                        float* __restrict__ dis) {
    int r = blockIdx.x * 256 + threadIdx.x;
    if (r >= NN) return;
    int s = rowstart[r], e = rowstart[r + 1];
    float d = 0.f;
    for (int i = s; i < e; ++i) d += __int_as_float(edge[i].y);
    dis[r] = d > 0.f ? rsqrtf(d) : 0.f;
}

// fused conversion: Xb = bf16(x); Xs8 = fp8_e4m3(dis * x).  NT stores (write-once).
__global__ void xconv_kernel(const float* __restrict__ x, const float* __restrict__ dis,
                             unsigned short* __restrict__ xb, unsigned int* __restrict__ xs8) {
    int i = blockIdx.x * 256 + threadIdx.x;   // NN*16 exact; 8 values/thread
    float d = dis[i >> 4];
    long long base = (long long)i * 8;
    f32x4 v0 = *(const f32x4*)(x + base);
    f32x4 v1 = *(const f32x4*)(x + base + 4);
    ushort8 o;
    #pragma unroll
    for (int k = 0; k < 4; ++k) { o[k] = f2bfu(v0[k]); o[4 + k] = f2bfu(v1[k]); }
    __builtin_nontemporal_store(o, (ushort8*)(xb + base));
    unsigned u0 = __builtin_amdgcn_cvt_pk_fp8_f32(d * v0[0], d * v0[1], 0, false);
    u0 = __builtin_amdgcn_cvt_pk_fp8_f32(d * v0[2], d * v0[3], u0, true);
    unsigned u1 = __builtin_amdgcn_cvt_pk_fp8_f32(d * v1[0], d * v1[1], 0, false);
    u1 = __builtin_amdgcn_cvt_pk_fp8_f32(d * v1[2], d * v1[3], u1, true);
    u32x2 ov; ov[0] = u0; ov[1] = u1;
    __builtin_nontemporal_store(ov, (u32x2*)(xs8 + (long long)i * 2));
}

// one wave per destination row, quarter-wave per edge, 2 edges in flight.
// fp8 source rows are pre-scaled by dis[c]: P[r] = -dis[r] * sum_e w_e * src8[c_e].
// MODE 0: dst = P(src); also emits dst8 = fp8(dis[r]*dst).  MODE 1: dst = 2*P(src) - x.
template <int MODE>
__launch_bounds__(256)
__global__ void gather_prop(const int* __restrict__ rowstart, const int2* __restrict__ edge,
                            const float* __restrict__ dis,
                            const unsigned int* __restrict__ src8,
                            const unsigned short* __restrict__ xb,
                            unsigned short* __restrict__ dstb,
                            unsigned int* __restrict__ dst8) {
    int gw   = (blockIdx.x << 2) + (threadIdx.x >> 6);   // row
    int lane = threadIdx.x & 63;
    int q = lane >> 4, fl = lane & 15;                   // quarter, 8B chunk
    int s = rowstart[gw], eend = rowstart[gw + 1];
    float a0[8] = {0.f,0.f,0.f,0.f,0.f,0.f,0.f,0.f};
    float a1[8] = {0.f,0.f,0.f,0.f,0.f,0.f,0.f,0.f};
    int e = s + q;
    for (; e + 4 < eend; e += 8) {   // 2 edges in flight per quarter
        int2 ed0 = edge[e];
        int2 ed1 = edge[e + 4];
        u32x2 v0 = *(const u32x2*)(src8 + ((long long)ed0.x << 5) + (fl << 1));
        u32x2 v1 = *(const u32x2*)(src8 + ((long long)ed1.x << 5) + (fl << 1));
        float w0 = __int_as_float(ed0.y);
        float w1 = __int_as_float(ed1.y);
        f32x2 p0 = __builtin_amdgcn_cvt_pk_f32_fp8(v0[0], false);
        f32x2 p1 = __builtin_amdgcn_cvt_pk_f32_fp8(v0[0], true);
        f32x2 p2 = __builtin_amdgcn_cvt_pk_f32_fp8(v0[1], false);
        f32x2 p3 = __builtin_amdgcn_cvt_pk_f32_fp8(v0[1], true);
        a0[0] += w0 * p0.x; a0[1] += w0 * p0.y; a0[2] += w0 * p1.x; a0[3] += w0 * p1.y;
        a0[4] += w0 * p2.x; a0[5] += w0 * p2.y; a0[6] += w0 * p3.x; a0[7] += w0 * p3.y;
        f32x2 r0 = __builtin_amdgcn_cvt_pk_f32_fp8(v1[0], false);
        f32x2 r1 = __builtin_amdgcn_cvt_pk_f32_fp8(v1[0], true);
        f32x2 r2 = __builtin_amdgcn_cvt_pk_f32_fp8(v1[1], false);
        f32x2 r3 = __builtin_amdgcn_cvt_pk_f32_fp8(v1[1], true);
        a1[0] += w1 * r0.x; a1[1] += w1 * r0.y; a1[2] += w1 * r1.x; a1[3] += w1 * r1.y;
        a1[4] += w1 * r2.x; a1[5] += w1 * r2.y; a1[6] += w1 * r3.x; a1[7] += w1 * r3.y;
    }
    if (e < eend) {
        int2 ed = edge[e];
        u32x2 v = *(const u32x2*)(src8 + ((long long)ed.x << 5) + (fl << 1));
        float w = __int_as_float(ed.y);
        f32x2 p0 = __builtin_amdgcn_cvt_pk_f32_fp8(v[0], false);
        f32x2 p1 = __builtin_amdgcn_cvt_pk_f32_fp8(v[0], true);
        f32x2 p2 = __builtin_amdgcn_cvt_pk_f32_fp8(v[1], false);
        f32x2 p3 = __builtin_amdgcn_cvt_pk_f32_fp8(v[1], true);
        a0[0] += w * p0.x; a0[1] += w * p0.y; a0[2] += w * p1.x; a0[3] += w * p1.y;
        a0[4] += w * p2.x; a0[5] += w * p2.y; a0[6] += w * p3.x; a0[7] += w * p3.y;
    }
    #pragma unroll
    for (int i = 0; i < 8; ++i) {
        a0[i] += a1[i];
        a0[i] += __shfl_xor(a0[i], 16);
        a0[i] += __shfl_xor(a0[i], 32);
    }
    if (lane < 16) {
        float sr = -dis[gw];
        if (MODE == 1) {
            ushort8 xv = *(const ushort8*)(xb + ((long long)gw << 7) + (fl << 3));
            ushort8 o;
            #pragma unroll
            for (int i = 0; i < 8; ++i) o[i] = f2bfu(2.f * sr * a0[i] - bf2f(xv[i]));
            __builtin_nontemporal_store(o, (ushort8*)(dstb + ((long long)gw << 7) + (fl << 3)));
        } else {
            float t[8];
            ushort8 o;
            #pragma unroll
            for (int i = 0; i < 8; ++i) { t[i] = sr * a0[i]; o[i] = f2bfu(t[i]); }
            __builtin_nontemporal_store(o, (ushort8*)(dstb + ((long long)gw << 7) + (fl << 3)));
            float ds = dis[gw];
            unsigned u0 = __builtin_amdgcn_cvt_pk_fp8_f32(ds * t[0], ds * t[1], 0, false);
            u0 = __builtin_amdgcn_cvt_pk_fp8_f32(ds * t[2], ds * t[3], u0, true);
            unsigned u1 = __builtin_amdgcn_cvt_pk_fp8_f32(ds * t[4], ds * t[5], 0, false);
            u1 = __builtin_amdgcn_cvt_pk_fp8_f32(ds * t[6], ds * t[7], u1, true);
            u32x2 ov; ov[0] = u0; ov[1] = u1;
            __builtin_nontemporal_store(ov, (u32x2*)(dst8 + ((long long)gw << 5) + (fl << 1)));
        }
    }
}

// ---------------------------------------------------------------------------
// Weight prep: pack W into MFMA B-fragment order.
// Frag unit (tile t, kstep ks) of scale s at unit index fb(s) + t*nk + ks,
// nk = 4(s+1), fb = {0, 52, 156}.  Lane l holds W_s[k=ks*32+(l>>4)*8+i][col=t*16+(l&15)].
// ---------------------------------------------------------------------------
__global__ void wprep_frag(const float* __restrict__ W1, const float* __restrict__ W2,
                           const float* __restrict__ W3, short* __restrict__ Wf) {
    __shared__ float lds[32 * 200];
    int bid = blockIdx.x;
    int s, ks;
    if (bid < 4)       { s = 0; ks = bid; }
    else if (bid < 12) { s = 1; ks = bid - 4; }
    else               { s = 2; ks = bid - 12; }
    const float* W = (s == 0) ? W1 : ((s == 1) ? W2 : W3);
    int p = ks >> 2;
    const float* Wp = W + (p * 128 + (ks & 3) * 32) * 200;
    for (int e = threadIdx.x; e < 6400; e += 256) lds[e] = Wp[e];
    __syncthreads();
    int nk = (s + 1) * 4;
    int fb = (s == 0) ? 0 : ((s == 1) ? 52 : 156);
    for (int qq = threadIdx.x; qq < 13 * 64; qq += 256) {
        int t = qq >> 6, lane = qq & 63;
        int col = t * 16 + (lane & 15);
        int kb  = (lane >> 4) * 8;
        short8 v;
        #pragma unroll
        for (int i = 0; i < 8; ++i) {
            float f = (col < FOUT) ? lds[(kb + i) * 200 + col] : 0.f;
            v[i] = f2bf(f);
        }
        *(short8*)&Wf[(fb + t * nk + ks) * 512 + lane * 8] = v;
    }
}

// ---------------------------------------------------------------------------
// Fused GEMM: 512 threads = 8 waves, BM=64, all 3 scales in one pass; 39
// units statically partitioned; B-frags reg-dbuf'd; LDS-transpose epilogue
// with NT full-row stores.  EPAD=204 -> 52224B LDS.
// ---------------------------------------------------------------------------
__constant__ int u_sc[8][5] = {
    {2,2,1,0,0}, {2,2,1,0,0}, {2,2,1,0,0}, {2,2,1,0,0},
    {2,2,1,0,0}, {2,2,1,0,0}, {2,1,1,1,0}, {1,1,1,1,-1}};
__constant__ int u_t[8][5] = {
    {0,1,0,0,1},     {2,3,1,2,3},    {4,5,2,4,5},    {6,7,3,6,7},
    {8,9,4,8,9},     {10,11,5,10,11},{12,6,7,8,12},  {9,10,11,12,0}};

#define EPAD 204   // f32 row stride in epilogue LDS (52224B total)

__launch_bounds__(512, 2)
__global__ void gemm_fused(const unsigned short* __restrict__ xb,
                           const unsigned short* __restrict__ t1b,
                           const unsigned short* __restrict__ t2b,
                           const short* __restrict__ Wf,
                           const float* __restrict__ b1, const float* __restrict__ b2,
                           const float* __restrict__ b3, float* __restrict__ out) {
    __shared__ __align__(16) char smem[64 * EPAD * 4];   // 52224B >= 49152B As
    short* As = (short*)smem;                             // [3][64][16 chunks][8]
    float* Ef = (float*)smem;                             // [64][EPAD]

    const int tid  = threadIdx.x;
    const int wave = tid >> 6;
    const int lane = tid & 63;
    const int l15  = lane & 15;
    const int lhi  = lane >> 4;
    const int b0   = blockIdx.x * 64;

    const unsigned short* panels[3] = {xb, t1b, t2b};
    #pragma unroll
    for (int i = 0; i < 6; ++i) {
        int q   = i * 512 + tid;
        int p   = q >> 10;
        int rem = q & 1023;
        int row = rem >> 4;
        int ch  = rem & 15;
        uint32x4 v = *(const uint32x4*)(panels[p] + ((long long)(b0 + row) << 7) + (ch << 3));
        *(uint32x4*)&As[((p * 64 + row) * 16 + (ch ^ (row & 7))) * 8] = v;
    }

    int usc[5], ubase[5], ucol0[5];
    #pragma unroll
    for (int j = 0; j < 5; ++j) {
        int sc = u_sc[wave][j], t = u_t[wave][j];
        usc[j]   = sc;
        ucol0[j] = t * 16;
        int nk = 4 * (sc + 1);
        int fb = (sc == 0) ? 0 : ((sc == 1) ? 52 : 156);
        ubase[j] = fb + t * nk;
    }

    f32x4 acc[5][4];
    #pragma unroll
    for (int j = 0; j < 5; ++j)
        #pragma unroll
        for (int m = 0; m < 4; ++m) acc[j][m] = {0.f, 0.f, 0.f, 0.f};

    short8 bf[2][5];
    #pragma unroll
    for (int j = 0; j < 5; ++j)
        bf[0][j] = *(const short8*)(Wf + (long long)(ubase[j] + 0) * 512 + lane * 8);

    __syncthreads();

    #pragma unroll
    for (int step = 0; step < 12; ++step) {
        const int p   = step >> 2;
        const int k4  = step & 3;
        const int cur = step & 1;
        if (step < 11) {
            #pragma unroll
            for (int j = 0; j < 5; ++j)
                bf[cur ^ 1][j] = *(const short8*)(Wf + (long long)(ubase[j] + step + 1) * 512 + lane * 8);
        }
        short8 af[4];
        #pragma unroll
        for (int m = 0; m < 4; ++m) {
            int row = m * 16 + l15;
            int ch  = (k4 * 4 + lhi) ^ (row & 7);
            af[m] = *(const short8*)&As[((p * 64 + row) * 16 + ch) * 8];
        }
        #pragma unroll
        for (int j = 0; j < 5; ++j) {
            if (usc[j] >= p) {   // wave-uniform branch; -1 sentinel never passes
                #pragma unroll
                for (int m = 0; m < 4; ++m)
                    acc[j][m] = __builtin_amdgcn_mfma_f32_16x16x32_bf16(af[m], bf[cur][j], acc[j][m], 0, 0, 0);
            }
        }
    }

    // epilogue: per scale, deposit to LDS then NT-store coalesced full rows
    #pragma unroll 1
    for (int sc = 0; sc < 3; ++sc) {
        __syncthreads();
        const float* bias = (sc == 0) ? b1 : ((sc == 1) ? b2 : b3);
        #pragma unroll
        for (int j = 0; j < 5; ++j) {
            if (usc[j] == sc) {
                int col = ucol0[j] + l15;
                if (col < FOUT) {
                    float bv = bias[col];
                    #pragma unroll
                    for (int m = 0; m < 4; ++m) {
                        int rbase = m * 16 + lhi * 4;
                        #pragma unroll
                        for (int jj = 0; jj < 4; ++jj)
                            Ef[(rbase + jj) * EPAD + col] = acc[j][m][jj] + bv;
                    }
                }
            }
        }
        __syncthreads();
        float* op = out + (long long)sc * NN * FOUT;
        for (int c = tid; c < 3200; c += 512) {   // 64 rows x 50 f32x4 chunks
            int r = c / 50, pos = c % 50;
            int row = b0 + r;
            if (row < NN) {
                f32x4 v = *(const f32x4*)&Ef[r * EPAD + pos * 4];
                __builtin_nontemporal_store(v, (f32x4*)&op[(long long)row * FOUT + pos * 4]);
            }
        }
    }
}

extern "C" void kernel_launch(void* const* d_in, const int* in_sizes, int n_in,
                              void* d_out, int out_size, void* d_ws, size_t ws_size,
                              hipStream_t stream) {
    const float* x  = (const float*)d_in[0];
    const void*  ei = d_in[1];
    const float* ew = (const float*)d_in[2];
    const float* W1 = (const float*)d_in[3];
    const float* b1 = (const float*)d_in[4];
    const float* W2 = (const float*)d_in[5];
    const float* b2 = (const float*)d_in[6];
    const float* W3 = (const float*)d_in[7];
    const float* b3 = (const float*)d_in[8];
    float* out = (float*)d_out;

    char* ws = (char*)d_ws;
    // layout (bytes):
    // [0,16)                  flag          } zeroed
    // [16, 3200016)           cnt8 8xN i32  } zeroed
    // [3600016, 4000032)      rowstart N+1 (padded)
    // [4000032, 4002080)      bsum 512
    // [4002080, 4402080)      dis  N f32
    // [4402080, 17202080)     edge int2 E
    // [17202080, 42826656)    Xb   bf16 NROWP*128
    // [42826656, 68451232)    T1b  bf16
    // [68451232, 94075808)    T2b  bf16
    // [94075808, 94395296)    Wf   bf16 frags (312 KB)
    // [94395296, 107207584)   Xs8  fp8 NROWP*128
    // [107207584, 120019872)  T1s8 fp8 NROWP*128
    int*   flag     = (int*)(ws + 0);
    int*   cnt8     = (int*)(ws + 16);
    int*   rowstart = (int*)(ws + 3600016);
    int*   bsum     = (int*)(ws + 4000032);
    float* dis      = (float*)(ws + 4002080);
    int2*  edge     = (int2*)(ws + 4402080);
    unsigned short* Xb  = (unsigned short*)(ws + 17202080);
    unsigned short* T1b = (unsigned short*)(ws + 42826656);
    unsigned short* T2b = (unsigned short*)(ws + 68451232);
    short* Wf       = (short*)(ws + 94075808);
    unsigned int* Xs8  = (unsigned int*)(ws + 94395296);
    unsigned int* T1s8 = (unsigned int*)(ws + 107207584);

    hipMemsetAsync(d_ws, 0, 3200016, stream);   // flag + cnt8

    detect_kernel<<<16, 256, 0, stream>>>((const long long*)ei, flag);
    cnt8_kernel<<<NE / 256, 256, 0, stream>>>(ei, flag, cnt8);
    scan_block<<<NBLK, 256, 0, stream>>>(cnt8, rowstart, bsum);
    scan_bsums<<<1, 512, 0, stream>>>(bsum);
    scan_add<<<NBLK + 1, 256, 0, stream>>>(rowstart, bsum);
    fill_csr<<<NE / 256, 256, 0, stream>>>(ei, flag, ew, rowstart, cnt8, edge);
    deg_seg<<<NBLK, 256, 0, stream>>>(rowstart, edge, dis);
    xconv_kernel<<<6250, 256, 0, stream>>>(x, dis, Xb, Xs8);
    gather_prop<0><<<NN / 4, 256, 0, stream>>>(rowstart, edge, dis, Xs8, nullptr, T1b, T1s8);
    gather_prop<1><<<NN / 4, 256, 0, stream>>>(rowstart, edge, dis, T1s8, Xb, T2b, nullptr);
    wprep_frag<<<24, 256, 0, stream>>>(W1, W2, W3, Wf);
    gemm_fused<<<1563, 512, 0, stream>>>(Xb, T1b, T2b, Wf, b1, b2, b3, out);
}